// Round 4
// baseline (124378.503 us; speedup 1.0000x reference)
//
#include <hip/hip_runtime.h>
#include <stdint.h>

#define SEQ   512
#define BATCH 64
#define INP   64
#define HID   1024
#define NBLK  256   // 4 hidden units per block
#define NTHR  512   // 8 waves = K-slice eighths; waves 0..3 also own unit u=w for the cell
#define NWAVE 8

// ---- relaxed agent-scope (cross-XCD coherent, L2-bypassing) accessors ----
__device__ __forceinline__ float ld_cg(const float* p) {
    return __hip_atomic_load(p, __ATOMIC_RELAXED, __HIP_MEMORY_SCOPE_AGENT);
}
__device__ __forceinline__ void st_cg(float* p, float v) {
    __hip_atomic_store(p, v, __ATOMIC_RELAXED, __HIP_MEMORY_SCOPE_AGENT);
}

// ---- grid barrier: NO threadfence (that was the R3 killer — it evicted L2 weights
// every step). Ordering: each wave's vmcnt drains at __syncthreads, so all sc1 h
// stores are IF-visible before tid0's flag store issues. Poll loop proved (R1/R3)
// that relaxed agent atomics observe remote updates with no fences.
__device__ __forceinline__ void gbar(uint32_t* flags, uint32_t val, int tid) {
    __syncthreads();
    if (tid == 0)
        __hip_atomic_store(&flags[blockIdx.x], val, __ATOMIC_RELAXED, __HIP_MEMORY_SCOPE_AGENT);
    if (tid < 64) {
        for (;;) {
            bool ok = true;
            #pragma unroll
            for (int i = 0; i < NBLK / 64; ++i) {
                uint32_t v = __hip_atomic_load(&flags[tid + i * 64], __ATOMIC_RELAXED,
                                               __HIP_MEMORY_SCOPE_AGENT);
                ok &= ((uint32_t)(v - val) < 0x10000000u);   // poison/stale-safe window
            }
            if (__all(ok)) break;
            __builtin_amdgcn_s_sleep(1);
        }
    }
    __syncthreads();
}

__device__ __forceinline__ float sigf(float x) { return 1.0f / (1.0f + __expf(-x)); }

// 16 FMAs for one k: weight = 4 consecutive float4 (u0:g0..3, u1, u2, u3), act broadcast.
__device__ __forceinline__ void fma16x(float av, const float4* __restrict__ w,
                                       float (&acc)[16]) {
    float4 w0 = w[0], w1 = w[1], w2 = w[2], w3 = w[3];
    acc[0]  += w0.x * av; acc[1]  += w0.y * av; acc[2]  += w0.z * av; acc[3]  += w0.w * av;
    acc[4]  += w1.x * av; acc[5]  += w1.y * av; acc[6]  += w1.z * av; acc[7]  += w1.w * av;
    acc[8]  += w2.x * av; acc[9]  += w2.y * av; acc[10] += w2.z * av; acc[11] += w2.w * av;
    acc[12] += w3.x * av; acc[13] += w3.y * av; acc[14] += w3.z * av; acc[15] += w3.w * av;
}

__device__ __forceinline__ void fma_chunk(const float (&a)[16], const float4* __restrict__ w,
                                          float (&acc)[16]) {
    #pragma unroll
    for (int i = 0; i < 16; ++i) fma16x(a[i], w + i * 4, acc);
}

// GEMV over h stored [k][64b]: per-lane stride-64 sc1 dwords, double-buffered chunks of 16 k.
// wp: float4 base for this k-range (4 float4 per k).
template <int NCHUNK>
__device__ __forceinline__ void gemv_h(const float* __restrict__ hp,     // hr + k0*64 + b
                                       const float4* __restrict__ wp,
                                       float (&acc)[16]) {
    float A[16], B[16];
    #pragma unroll
    for (int i = 0; i < 16; ++i) A[i] = ld_cg(hp + i * 64);
    #pragma unroll 1
    for (int c = 0; c < NCHUNK; c += 2) {
        #pragma unroll
        for (int i = 0; i < 16; ++i) B[i] = ld_cg(hp + (c * 16 + 16 + i) * 64);
        fma_chunk(A, wp + c * 64, acc);
        if (c + 2 < NCHUNK) {
            #pragma unroll
            for (int i = 0; i < 16; ++i) A[i] = ld_cg(hp + (c * 16 + 32 + i) * 64);
        }
        fma_chunk(B, wp + (c + 1) * 64, acc);
    }
}

// GEMV over per-lane-contiguous activations (normal cached float4 loads), chunks of 16 k.
template <int NCHUNK>
__device__ __forceinline__ void gemv_x(const float4* __restrict__ xp,
                                       const float4* __restrict__ wp,
                                       float (&acc)[16]) {
    float4 A[4], B[4];
    #pragma unroll
    for (int q = 0; q < 4; ++q) A[q] = xp[q];
    #pragma unroll 1
    for (int c = 0; c < NCHUNK; c += 2) {
        #pragma unroll
        for (int q = 0; q < 4; ++q) B[q] = xp[c * 4 + 4 + q];
        #pragma unroll
        for (int q = 0; q < 4; ++q) {
            const float4 v = A[q];
            fma16x(v.x, wp + (c * 16 + q * 4 + 0) * 4, acc);
            fma16x(v.y, wp + (c * 16 + q * 4 + 1) * 4, acc);
            fma16x(v.z, wp + (c * 16 + q * 4 + 2) * 4, acc);
            fma16x(v.w, wp + (c * 16 + q * 4 + 3) * 4, acc);
        }
        if (c + 2 < NCHUNK) {
            #pragma unroll
            for (int q = 0; q < 4; ++q) A[q] = xp[c * 4 + 8 + q];
        }
        #pragma unroll
        for (int q = 0; q < 4; ++q) {
            const float4 v = B[q];
            fma16x(v.x, wp + ((c + 1) * 16 + q * 4 + 0) * 4, acc);
            fma16x(v.y, wp + ((c + 1) * 16 + q * 4 + 1) * 4, acc);
            fma16x(v.z, wp + ((c + 1) * 16 + q * 4 + 2) * 4, acc);
            fma16x(v.w, wp + ((c + 1) * 16 + q * 4 + 3) * 4, acc);
        }
    }
}

// ---- pack layer-0 weights: per (bk, wave, lk): 16 floats (u0g0..3,u1,u2,u3).
// wave stream = 136 kc: lk<8 -> x-part k=w*8+lk (Wih0, K=64); lk>=8 -> h k=w*128+(lk-8).
__global__ void __launch_bounds__(256) pack_A(const float* __restrict__ Wih,
                                              const float* __restrict__ Whh,
                                              float* __restrict__ Wp) {
    int idx = blockIdx.x * 256 + threadIdx.x;     // [0, 256*8*136)
    int lk = idx % 136, bw = idx / 136;
    int w = bw & 7, bk = bw >> 3, j0 = bk * 4;
    float v[16];
    #pragma unroll
    for (int u = 0; u < 4; ++u)
        #pragma unroll
        for (int g = 0; g < 4; ++g) {
            int row = g * HID + j0 + u;
            v[u * 4 + g] = (lk < 8) ? Wih[(size_t)row * INP + (w * 8 + lk)]
                                    : Whh[(size_t)row * HID + (w * 128 + lk - 8)];
        }
    float4* o = (float4*)(Wp + (size_t)idx * 16);
    o[0] = make_float4(v[0], v[1], v[2], v[3]);
    o[1] = make_float4(v[4], v[5], v[6], v[7]);
    o[2] = make_float4(v[8], v[9], v[10], v[11]);
    o[3] = make_float4(v[12], v[13], v[14], v[15]);
}

// ---- pack layer-1 weights: wave stream = 256 kc; kc = w*256+lk; kc<1024 -> Wih1, else Whh1.
__global__ void __launch_bounds__(256) pack_B(const float* __restrict__ Wih,
                                              const float* __restrict__ Whh,
                                              float* __restrict__ Wp) {
    int idx = blockIdx.x * 256 + threadIdx.x;     // [0, 256*8*256)
    int lk = idx & 255, bw = idx >> 8;
    int w = bw & 7, bk = bw >> 3, j0 = bk * 4;
    int kc = w * 256 + lk;
    float v[16];
    #pragma unroll
    for (int u = 0; u < 4; ++u)
        #pragma unroll
        for (int g = 0; g < 4; ++g) {
            int row = g * HID + j0 + u;
            v[u * 4 + g] = (kc < 1024) ? Wih[(size_t)row * HID + kc]
                                       : Whh[(size_t)row * HID + (kc - 1024)];
        }
    float4* o = (float4*)(Wp + (size_t)idx * 16);
    o[0] = make_float4(v[0], v[1], v[2], v[3]);
    o[1] = make_float4(v[4], v[5], v[6], v[7]);
    o[2] = make_float4(v[8], v[9], v[10], v[11]);
    o[3] = make_float4(v[12], v[13], v[14], v[15]);
}

// ================= Phase A: layer-0 scan =================
__global__ void __launch_bounds__(NTHR, 2) lstm_phaseA(
    const float* __restrict__ x, const float* __restrict__ bih,
    const float* __restrict__ bhh, const float* __restrict__ Wp,
    float* __restrict__ out, float* __restrict__ hbuf, uint32_t* __restrict__ flags)
{
    __shared__ float red[NWAVE][16][64];   // 32 KB
    const int tid = threadIdx.x, bk = blockIdx.x;
    const int w = tid >> 6, b = tid & 63;
    const float4* wpb = (const float4*)Wp + (size_t)(bk * NWAVE + w) * 136 * 4;

    float bias[4] = {0, 0, 0, 0};
    int j = 0;
    if (w < 4) {
        j = bk * 4 + w;
        #pragma unroll
        for (int g = 0; g < 4; ++g) bias[g] = bih[g * HID + j] + bhh[g * HID + j];
        st_cg(&hbuf[j * 64 + b], 0.0f);    // h(-1)=0 in buffer 0
    }
    float c_ = 0.0f;
    gbar(flags, 1u, tid);

    for (int t = 0; t < SEQ; ++t) {
        const float* hr = hbuf + (t & 1) * (HID * 64);
        float*       hw = hbuf + ((t & 1) ^ 1) * (HID * 64);
        float acc[16];
        #pragma unroll
        for (int i = 0; i < 16; ++i) acc[i] = 0.0f;

        // x-part: 8 kc, act = x[t][b][w*8 .. w*8+8)  (L2-cached normal loads)
        const float* xq = x + ((size_t)t * BATCH + b) * INP + w * 8;
        float4 xv0 = *(const float4*)xq;
        float4 xv1 = *(const float4*)(xq + 4);
        fma16x(xv0.x, wpb + 0 * 4, acc);  fma16x(xv0.y, wpb + 1 * 4, acc);
        fma16x(xv0.z, wpb + 2 * 4, acc);  fma16x(xv0.w, wpb + 3 * 4, acc);
        fma16x(xv1.x, wpb + 4 * 4, acc);  fma16x(xv1.y, wpb + 5 * 4, acc);
        fma16x(xv1.z, wpb + 6 * 4, acc);  fma16x(xv1.w, wpb + 7 * 4, acc);

        // h-part: 128 kc starting at k0 = w*128 (sc1 loads, IF-coherent)
        gemv_h<8>(hr + (w * 128) * 64 + b, wpb + 8 * 4, acc);

        #pragma unroll
        for (int i = 0; i < 16; ++i) red[w][i][b] = acc[i];
        __syncthreads();
        if (w < 4) {
            float g4[4];
            #pragma unroll
            for (int g = 0; g < 4; ++g) {
                float s = bias[g];
                #pragma unroll
                for (int ww = 0; ww < NWAVE; ++ww) s += red[ww][w * 4 + g][b];
                g4[g] = s;
            }
            float ig = sigf(g4[0]), fg = sigf(g4[1]), gg = tanhf(g4[2]), og = sigf(g4[3]);
            c_ = fg * c_ + ig * gg;
            float h = og * tanhf(c_);
            st_cg(&hw[j * 64 + b], h);
            out[((size_t)t * BATCH + b) * HID + j] = h;   // park h1 in d_out
        }
        if (t < SEQ - 1) gbar(flags, (uint32_t)(t + 2), tid);
    }
}

// ================= Phase B: layer-1 scan + y_pred =================
__global__ void __launch_bounds__(NTHR, 2) lstm_phaseB(
    const float* __restrict__ bih, const float* __restrict__ bhh,
    const float* __restrict__ Wlin, const float* __restrict__ blin,
    const float* __restrict__ Wp, float* __restrict__ out,
    float* __restrict__ hbuf, uint32_t* __restrict__ flags)
{
    __shared__ float red[NWAVE][16][64];   // 32 KB
    const int tid = threadIdx.x, bk = blockIdx.x;
    const int w = tid >> 6, b = tid & 63;
    const float4* wpb = (const float4*)Wp + (size_t)(bk * NWAVE + w) * 256 * 4;

    float bias[4] = {0, 0, 0, 0};
    int j = 0;
    if (w < 4) {
        j = bk * 4 + w;
        #pragma unroll
        for (int g = 0; g < 4; ++g) bias[g] = bih[g * HID + j] + bhh[g * HID + j];
        st_cg(&hbuf[j * 64 + b], 0.0f);
    }
    float c_ = 0.0f, hout = 0.0f;
    gbar(flags, 1u, tid);

    for (int t = 0; t < SEQ; ++t) {
        if (w < 4 && t > 0)   // deferred h2 write: slice t-1's readers finished at step t-1
            out[((size_t)(t - 1) * BATCH + b) * HID + j] = hout;
        const float* hr = hbuf + (t & 1) * (HID * 64);
        float*       hw = hbuf + ((t & 1) ^ 1) * (HID * 64);
        float acc[16];
        #pragma unroll
        for (int i = 0; i < 16; ++i) acc[i] = 0.0f;

        if (w < 4) {
            // x-part: kc = w*256 .. +256, act = h1 from out[t] (written by phase A kernel,
            // normal cached loads)
            gemv_x<16>((const float4*)(out + ((size_t)t * BATCH + b) * HID + w * 256),
                       wpb, acc);
        } else {
            // h-part: k0 = (w-4)*256 (sc1 loads)
            gemv_h<16>(hr + ((w - 4) * 256) * 64 + b, wpb, acc);
        }

        #pragma unroll
        for (int i = 0; i < 16; ++i) red[w][i][b] = acc[i];
        __syncthreads();
        if (w < 4) {
            float g4[4];
            #pragma unroll
            for (int g = 0; g < 4; ++g) {
                float s = bias[g];
                #pragma unroll
                for (int ww = 0; ww < NWAVE; ++ww) s += red[ww][w * 4 + g][b];
                g4[g] = s;
            }
            float ig = sigf(g4[0]), fg = sigf(g4[1]), gg = tanhf(g4[2]), og = sigf(g4[3]);
            c_ = fg * c_ + ig * gg;
            float h = og * tanhf(c_);
            st_cg(&hw[j * 64 + b], h);
            hout = h;
        }
        gbar(flags, (uint32_t)(t + 2), tid);
    }
    if (w < 4) out[((size_t)(SEQ - 1) * BATCH + b) * HID + j] = hout;

    // y_pred = h2[T-1] @ W_lin^T + b_lin  (final h2 is in hbuf buffer 0; sc1 reads)
    if (bk == 0 && tid < 64) {
        float acc0 = blin[0];
        #pragma unroll 8
        for (int k = 0; k < HID; ++k) acc0 += ld_cg(&hbuf[k * 64 + tid]) * Wlin[k];
        out[(size_t)SEQ * BATCH * HID + tid] = acc0;
    }
}

extern "C" void kernel_launch(void* const* d_in, const int* in_sizes, int n_in,
                              void* d_out, int out_size, void* d_ws, size_t ws_size,
                              hipStream_t stream) {
    const float* x    = (const float*)d_in[0];
    const float* Wih0 = (const float*)d_in[1];
    const float* Whh0 = (const float*)d_in[2];
    const float* bih0 = (const float*)d_in[3];
    const float* bhh0 = (const float*)d_in[4];
    const float* Wih1 = (const float*)d_in[5];
    const float* Whh1 = (const float*)d_in[6];
    const float* bih1 = (const float*)d_in[7];
    const float* bhh1 = (const float*)d_in[8];
    const float* Wlin = (const float*)d_in[9];
    const float* blin = (const float*)d_in[10];
    float* out = (float*)d_out;

    // ws layout (floats): hA[131072] hB[131072] flagsA[256]+flagsB[256] (as u32) Wp[8.39M]
    float* ws = (float*)d_ws;
    float* hA = ws;
    float* hB = ws + 2 * HID * BATCH;
    uint32_t* flagsA = (uint32_t*)(ws + 4 * HID * BATCH);
    uint32_t* flagsB = flagsA + NBLK;
    float* Wp = ws + 4 * HID * BATCH + 512;          // shared by phase A then phase B
    // total: 262656 + 8388608 floats = 34.6 MB

    pack_A<<<dim3(1088), dim3(256), 0, stream>>>(Wih0, Whh0, Wp);
    lstm_phaseA<<<dim3(NBLK), dim3(NTHR), 0, stream>>>(
        x, bih0, bhh0, Wp, out, hA, flagsA);
    pack_B<<<dim3(2048), dim3(256), 0, stream>>>(Wih1, Whh1, Wp);   // after phase A (stream-ordered)
    lstm_phaseB<<<dim3(NBLK), dim3(NTHR), 0, stream>>>(
        bih1, bhh1, Wlin, blin, Wp, out, hB, flagsB);
}